// Round 8
// baseline (733.186 us; speedup 1.0000x reference)
//
#include <hip/hip_runtime.h>

#define NN 50000
#define NE 1600000
#define NFEAT 512
#define NHID 64
#define H1 8
#define NCLASS 16
#define ALPHA 0.2f

typedef __attribute__((ext_vector_type(8))) short short8;
typedef __attribute__((ext_vector_type(4))) float floatx4;

__device__ __forceinline__ float elu_f(float x) { return x > 0.0f ? x : expf(x) - 1.0f; }
__device__ __forceinline__ float edge_w(float logit) {
    return expf(-fmaxf(logit, ALPHA * logit));   // exp(-leaky_relu)
}
__device__ __forceinline__ ushort f2bf(float f) {
    uint u = __float_as_uint(f);
    return (ushort)((u + 0x7FFFu + ((u >> 16) & 1)) >> 16);   // RNE
}
__device__ __forceinline__ uint packbf2(float lo, float hi) {
    return (uint)f2bf(lo) | ((uint)f2bf(hi) << 16);
}
__device__ __forceinline__ float bflo(uint v) { return __uint_as_float(v << 16); }
__device__ __forceinline__ float bfhi(uint v) { return __uint_as_float(v & 0xFFFF0000u); }

// ---------------- phase 0 merged: pack W1 | pack W2^T | degree hist ----------------
#define PACK_BLKS 1024
#define PACK2_BLKS 32
#define DEG_BLKS  6250
__global__ __launch_bounds__(256) void prep_k(const float* __restrict__ W1,
                                              ushort* __restrict__ Wt,
                                              const float* __restrict__ W2,
                                              ushort* __restrict__ W2tb,
                                              const int* __restrict__ ei,
                                              int* __restrict__ deg) {
    int b = blockIdx.x;
    if (b < PACK_BLKS) {
        int i = b * 256 + threadIdx.x;
        int c = i >> 9, k = i & 511;
        int head = c >> 6, hid = c & 63;
        Wt[i] = f2bf(W1[(head * 512 + k) * 64 + hid]);
    } else if (b < PACK_BLKS + PACK2_BLKS) {
        int i = (b - PACK_BLKS) * 256 + threadIdx.x;   // i = c*512 + f
        int c = i >> 9, f = i & 511;
        W2tb[i] = f2bf(W2[f * 16 + c]);
    } else {
        int e = (b - PACK_BLKS - PACK2_BLKS) * 256 + threadIdx.x;
        if (e < NE) atomicAdd(&deg[ei[e]], 1);
    }
}

// ---------------- parallel exclusive scan of deg -> rowptr (2 kernels) ----------------
#define SCAN_BLKS 196
__global__ __launch_bounds__(256) void scanA_k(const int* __restrict__ deg,
                                               int* __restrict__ rowptr,
                                               int* __restrict__ bsum) {
    __shared__ int wsum[4];
    const int t = threadIdx.x, lane = t & 63, wv = t >> 6;
    int i = blockIdx.x * 256 + t;
    int v = (i < NN) ? deg[i] : 0;
    int s = v;
#pragma unroll
    for (int o = 1; o < 64; o <<= 1) {
        int u = __shfl_up(s, o);
        if (lane >= o) s += u;
    }
    if (lane == 63) wsum[wv] = s;
    __syncthreads();
    if (t == 0) { wsum[1] += wsum[0]; wsum[2] += wsum[1]; wsum[3] += wsum[2]; }
    __syncthreads();
    int excl = s - v + (wv > 0 ? wsum[wv - 1] : 0);
    if (i < NN) rowptr[i] = excl;
    if (t == 255) bsum[blockIdx.x] = wsum[3];
}

// each block sums bsum[0..blockIdx.x-1] itself, then offsets its rowptr range
__global__ __launch_bounds__(256) void scanBC_k(int* __restrict__ rowptr,
                                                const int* __restrict__ bsum) {
    __shared__ int ws[4];
    const int t = threadIdx.x, lane = t & 63, wv = t >> 6;
    int v = (t < SCAN_BLKS && t < (int)blockIdx.x) ? bsum[t] : 0;
#pragma unroll
    for (int o = 1; o < 64; o <<= 1) v += __shfl_xor(v, o);
    if (lane == 0) ws[wv] = v;
    __syncthreads();
    int tot = ws[0] + ws[1] + ws[2] + ws[3];
    int i = blockIdx.x * 256 + t;
    if (i < NN) rowptr[i] += tot;
    if (i == 0) rowptr[NN] = NE;
}

__global__ __launch_bounds__(256) void scatter_k(const int* __restrict__ ei,
                                                 const int* __restrict__ rowptr,
                                                 int* __restrict__ cursor,
                                                 ushort* __restrict__ csru) {
    int e = blockIdx.x * 256 + threadIdx.x;
    if (e < NE) {
        int src = ei[e];
        int pos = rowptr[src] + atomicAdd(&cursor[src], 1);
        csru[pos] = (ushort)ei[NE + e];
    }
}

// ---------------- GEMM1 (bf16 MFMA) 128x256 tile, reads fp32 x directly ----------------
// grid (2, 391). In-staging fp32->bf16 pack. Fused per-head attention scores.
__global__ __launch_bounds__(256) void gemm1_k(const float* __restrict__ x,
                                               const ushort* __restrict__ Wt,
                                               const float* __restrict__ a1,
                                               ushort* __restrict__ h1b,
                                               float* __restrict__ s1s,
                                               float* __restrict__ s1d) {
    __shared__ ushort As[128 * 32];   // [m][k]  8 KB
    __shared__ ushort Bs[256 * 32];   // [c][k] 16 KB
    const int tid = threadIdx.x;
    const int wv = tid >> 6, lane = tid & 63;
    const int quad = lane >> 4, l16 = lane & 15;
    const int row0 = blockIdx.y * 128;
    const int col0 = blockIdx.x * 256;
    const int sm = tid >> 1, sk = (tid & 1) * 16;   // A: 16 floats/thread
    floatx4 acc[2][16];
#pragma unroll
    for (int rt = 0; rt < 2; rt++)
#pragma unroll
        for (int ct = 0; ct < 16; ct++) acc[rt][ct] = (floatx4){0.f, 0.f, 0.f, 0.f};

    for (int k0 = 0; k0 < 512; k0 += 32) {
        int r = row0 + sm;
        float4 f0 = {}, f1 = {}, f2 = {}, f3 = {};
        if (r < NN) {
            const float* xp = x + (size_t)r * 512 + k0 + sk;
            f0 = *(const float4*)xp;
            f1 = *(const float4*)(xp + 4);
            f2 = *(const float4*)(xp + 8);
            f3 = *(const float4*)(xp + 12);
        }
        uint4 pa, pb;
        pa.x = packbf2(f0.x, f0.y); pa.y = packbf2(f0.z, f0.w);
        pa.z = packbf2(f1.x, f1.y); pa.w = packbf2(f1.z, f1.w);
        pb.x = packbf2(f2.x, f2.y); pb.y = packbf2(f2.z, f2.w);
        pb.z = packbf2(f3.x, f3.y); pb.w = packbf2(f3.z, f3.w);
        *(uint4*)(As + sm * 32 + sk) = pa;
        *(uint4*)(As + sm * 32 + sk + 8) = pb;
        // B: one full 32-ushort column per thread (4 x uint4 = 32 ushorts)
        const ushort* wp = Wt + (size_t)(col0 + tid) * 512 + k0;
        *(uint4*)(Bs + tid * 32)      = *(const uint4*)wp;
        *(uint4*)(Bs + tid * 32 + 8)  = *(const uint4*)(wp + 8);
        *(uint4*)(Bs + tid * 32 + 16) = *(const uint4*)(wp + 16);
        *(uint4*)(Bs + tid * 32 + 24) = *(const uint4*)(wp + 24);
        __syncthreads();
        short8 a0 = *(const short8*)(As + (wv * 32 + l16) * 32 + quad * 8);
        short8 a1f = *(const short8*)(As + (wv * 32 + 16 + l16) * 32 + quad * 8);
#pragma unroll
        for (int ct = 0; ct < 16; ct++) {
            short8 bf = *(const short8*)(Bs + (ct * 16 + l16) * 32 + quad * 8);
            acc[0][ct] = __builtin_amdgcn_mfma_f32_16x16x32_bf16(a0, bf, acc[0][ct], 0, 0, 0);
            acc[1][ct] = __builtin_amdgcn_mfma_f32_16x16x32_bf16(a1f, bf, acc[1][ct], 0, 0, 0);
        }
        __syncthreads();
    }

#pragma unroll
    for (int rt = 0; rt < 2; rt++) {
        const int rbase = row0 + wv * 32 + rt * 16 + quad * 4;
        float ss[4][4] = {}, sd[4][4] = {};
#pragma unroll
        for (int ct = 0; ct < 16; ct++) {
            int colg = col0 + ct * 16 + l16;
            int head = colg >> 6;
            int hh = ct >> 2;
            float avs = a1[head * 128 + (colg & 63)];
            float avd = a1[head * 128 + 64 + (colg & 63)];
#pragma unroll
            for (int r = 0; r < 4; r++) {
                float v = acc[rt][ct][r];
                ss[hh][r] += v * avs;
                sd[hh][r] += v * avd;
                int row = rbase + r;
                if (row < NN) h1b[(size_t)row * 512 + colg] = f2bf(v);
            }
        }
#pragma unroll
        for (int hh = 0; hh < 4; hh++)
#pragma unroll
            for (int r = 0; r < 4; r++) {
                float a_ = ss[hh][r], b_ = sd[hh][r];
#pragma unroll
                for (int o = 1; o < 16; o <<= 1) {
                    a_ += __shfl_xor(a_, o);
                    b_ += __shfl_xor(b_, o);
                }
                int row = rbase + r;
                if (l16 == 0 && row < NN) {
                    int head = (col0 >> 6) + hh;
                    s1s[head * NN + row] = a_;
                    s1d[head * NN + row] = b_;
                }
            }
    }
}

// ---------------- fused layer-1 aggregation + GEMM2 + layer-2 scores ----------------
__global__ __launch_bounds__(256) void agg1f_k(const int* __restrict__ rowptr,
                                               const ushort* __restrict__ csru,
                                               const float* __restrict__ s1s,
                                               const float* __restrict__ s1d,
                                               const uint4* __restrict__ hb,
                                               const ushort* __restrict__ W2tb,
                                               const float* __restrict__ a2,
                                               float* __restrict__ h2,
                                               float* __restrict__ s2s,
                                               float* __restrict__ s2d) {
    __shared__ ushort Ash[16 * 512];
    const int tid = threadIdx.x;
    const int wv = tid >> 6, lane = tid & 63;
    const int n0 = blockIdx.x * 4;
    const int n = n0 + wv;              // NN % 4 == 0
    const int head8 = lane >> 3;
    const int esub = lane & 7;
    const int beg = rowptr[n];
    const int deg = rowptr[n + 1] - beg;
    const float ssrc = s1s[head8 * NN + n];
    float acc[8] = {};
    float rsum = 0.f;

    for (int k = 0; k < deg; k += 8) {
        int jc = min(k + esub, deg - 1);
        int dwj = csru[beg + jc];
        float w = edge_w(ssrc + s1d[head8 * NN + dwj]);
        if (k + esub >= deg) w = 0.f;
        rsum += w;
        int rem = deg - k;
        if (rem >= 8) {
            int dj[8];
#pragma unroll
            for (int j = 0; j < 8; j++) dj[j] = __shfl(dwj, j);
            uint4 v[8];
#pragma unroll
            for (int j = 0; j < 8; j++) v[j] = hb[(size_t)dj[j] * 64 + lane];
#pragma unroll
            for (int j = 0; j < 8; j++) {
                float wj = __shfl(w, (head8 << 3) + j);
                acc[0] += wj * bflo(v[j].x); acc[1] += wj * bfhi(v[j].x);
                acc[2] += wj * bflo(v[j].y); acc[3] += wj * bfhi(v[j].y);
                acc[4] += wj * bflo(v[j].z); acc[5] += wj * bfhi(v[j].z);
                acc[6] += wj * bflo(v[j].w); acc[7] += wj * bfhi(v[j].w);
            }
        } else {
            for (int j = 0; j < rem; j++) {
                int djs = __shfl(dwj, j);
                uint4 vv = hb[(size_t)djs * 64 + lane];
                float wj = __shfl(w, (head8 << 3) + j);
                acc[0] += wj * bflo(vv.x); acc[1] += wj * bfhi(vv.x);
                acc[2] += wj * bflo(vv.y); acc[3] += wj * bfhi(vv.y);
                acc[4] += wj * bflo(vv.z); acc[5] += wj * bfhi(vv.z);
                acc[6] += wj * bflo(vv.w); acc[7] += wj * bfhi(vv.w);
            }
        }
    }

    rsum += __shfl_xor(rsum, 1);
    rsum += __shfl_xor(rsum, 2);
    rsum += __shfl_xor(rsum, 4);
    float inv = 1.0f / rsum;
    uint4 o;
    o.x = packbf2(elu_f(acc[0] * inv), elu_f(acc[1] * inv));
    o.y = packbf2(elu_f(acc[2] * inv), elu_f(acc[3] * inv));
    o.z = packbf2(elu_f(acc[4] * inv), elu_f(acc[5] * inv));
    o.w = packbf2(elu_f(acc[6] * inv), elu_f(acc[7] * inv));
    *(uint4*)(Ash + wv * 512 + lane * 8) = o;
    __syncthreads();

    if (wv == 0) {
        const int l16 = lane & 15, q = lane >> 4;
        floatx4 c2 = (floatx4){0.f, 0.f, 0.f, 0.f};
#pragma unroll
        for (int s = 0; s < 16; s++) {
            short8 af = *(const short8*)(Ash + l16 * 512 + s * 32 + q * 8);
            short8 bf = *(const short8*)(W2tb + l16 * 512 + s * 32 + q * 8);
            c2 = __builtin_amdgcn_mfma_f32_16x16x32_bf16(af, bf, c2, 0, 0, 0);
        }
        if (q == 0) {
#pragma unroll
            for (int r = 0; r < 4; r++) h2[(size_t)(n0 + r) * 16 + l16] = c2[r];
        }
#pragma unroll
        for (int r = 0; r < 4; r++) {
            float ssv = c2[r] * a2[l16];
            float sdv = c2[r] * a2[16 + l16];
#pragma unroll
            for (int oo = 1; oo < 16; oo <<= 1) {
                ssv += __shfl_xor(ssv, oo);
                sdv += __shfl_xor(sdv, oo);
            }
            if (lane == 0) { s2s[n0 + r] = ssv; s2d[n0 + r] = sdv; }
        }
    }
}

// ---------------- layer-2 aggregation + fused log_softmax ----------------
__global__ __launch_bounds__(256) void agg2_k(const int* __restrict__ rowptr,
                                              const ushort* __restrict__ csru,
                                              const float* __restrict__ s2s,
                                              const float* __restrict__ s2d,
                                              const float* __restrict__ h2,
                                              float* __restrict__ out) {
    const int n = (blockIdx.x * 256 + threadIdx.x) >> 6;
    const int lane = threadIdx.x & 63;
    if (n >= NN) return;
    const int beg = rowptr[n], end = rowptr[n + 1];
    const float sn = s2s[n];
    const int sub = lane >> 4, f = lane & 15;
    float acc = 0.f, rsum = 0.f;
    int e = beg + sub;
    for (; e + 4 < end; e += 8) {          // 2 edges in flight per subgroup
        int d0 = csru[e], d1 = csru[e + 4];
        float t0 = s2d[d0], t1 = s2d[d1];
        float h0 = h2[(size_t)d0 * 16 + f], h1v = h2[(size_t)d1 * 16 + f];
        float w0 = edge_w(sn + t0), w1 = edge_w(sn + t1);
        acc += w0 * h0 + w1 * h1v;
        rsum += w0 + w1;
    }
    if (e < end) {
        int d0 = csru[e];
        float w0 = edge_w(sn + s2d[d0]);
        acc += w0 * h2[(size_t)d0 * 16 + f];
        rsum += w0;
    }
    acc += __shfl_down(acc, 32);
    acc += __shfl_down(acc, 16);
    rsum += __shfl_down(rsum, 32);
    rsum += __shfl_down(rsum, 16);
    if (lane < 16) {
        float v = elu_f(acc / rsum);
        float m = v;
#pragma unroll
        for (int o = 8; o > 0; o >>= 1) m = fmaxf(m, __shfl_xor(m, o));
        float ex = expf(v - m), s = ex;
#pragma unroll
        for (int o = 8; o > 0; o >>= 1) s += __shfl_xor(s, o);
        out[(size_t)n * 16 + f] = v - (logf(s) + m);
    }
}

extern "C" void kernel_launch(void* const* d_in, const int* in_sizes, int n_in,
                              void* d_out, int out_size, void* d_ws, size_t ws_size,
                              hipStream_t stream) {
    const float* x  = (const float*)d_in[0];
    const int*   ei = (const int*)d_in[1];
    const float* W1 = (const float*)d_in[2];
    const float* a1 = (const float*)d_in[3];
    const float* W2 = (const float*)d_in[4];
    const float* a2 = (const float*)d_in[5];
    float* out = (float*)d_out;

    ushort* h1b   = (ushort*)d_ws;                 // 25.6M ushort
    ushort* Wt    = h1b + (size_t)NN * 512;        // 262144
    ushort* W2tb  = Wt + 512 * 512;                // 8192
    float* s1s    = (float*)(W2tb + 8192);         // 400K floats
    float* s1d    = s1s + (size_t)NN * H1;         // 400K
    int* deg      = (int*)(s1d + (size_t)NN * H1); // 50000
    int* cursor   = deg + NN;                      // 50000
    int* rowptr   = cursor + NN;                   // 50001
    int* bsum     = rowptr + NN + 1;               // 196 (+pad)
    ushort* csru  = (ushort*)(bsum + 256);         // 1.6M ushort
    float* h2     = (float*)(csru + NE);           // 800K floats
    float* s2s    = h2 + (size_t)NN * 16;          // 50000
    float* s2d    = s2s + NN;                      // 50000

    hipMemsetAsync(deg, 0, 2 * NN * sizeof(int), stream);  // deg + cursor

    prep_k<<<PACK_BLKS + PACK2_BLKS + DEG_BLKS, 256, 0, stream>>>(W1, Wt, W2, W2tb, ei, deg);
    scanA_k<<<SCAN_BLKS, 256, 0, stream>>>(deg, rowptr, bsum);
    scanBC_k<<<SCAN_BLKS, 256, 0, stream>>>(rowptr, bsum);
    scatter_k<<<(NE + 255) / 256, 256, 0, stream>>>(ei, rowptr, cursor, csru);
    gemm1_k<<<dim3(2, 391), 256, 0, stream>>>(x, Wt, a1, h1b, s1s, s1d);
    agg1f_k<<<NN / 4, 256, 0, stream>>>(rowptr, csru, s1s, s1d,
                                        (const uint4*)h1b, W2tb, a2, h2, s2s, s2d);
    agg2_k<<<(NN + 3) / 4, 256, 0, stream>>>(rowptr, csru, s2s, s2d, h2, out);
}

// Round 10
// 685.225 us; speedup vs baseline: 1.0700x; 1.0700x over previous
//
#include <hip/hip_runtime.h>

#define NN 50000
#define NE 1600000
#define NFEAT 512
#define NHID 64
#define H1 8
#define NCLASS 16
#define ALPHA 0.2f

typedef __attribute__((ext_vector_type(8))) short short8;
typedef __attribute__((ext_vector_type(4))) float floatx4;

__device__ __forceinline__ float elu_f(float x) { return x > 0.0f ? x : expf(x) - 1.0f; }
__device__ __forceinline__ float edge_w(float logit) {
    return expf(-fmaxf(logit, ALPHA * logit));   // exp(-leaky_relu)
}
__device__ __forceinline__ ushort f2bf(float f) {
    uint u = __float_as_uint(f);
    return (ushort)((u + 0x7FFFu + ((u >> 16) & 1)) >> 16);   // RNE
}
__device__ __forceinline__ uint packbf2(float lo, float hi) {
    return (uint)f2bf(lo) | ((uint)f2bf(hi) << 16);
}
__device__ __forceinline__ float bflo(uint v) { return __uint_as_float(v << 16); }
__device__ __forceinline__ float bfhi(uint v) { return __uint_as_float(v & 0xFFFF0000u); }

// ------- phase 0 merged: cast x->bf16 | pack W1 | pack W2^T | degree hist -------
#define CAST_BLKS 12500
#define PACK_BLKS 1024
#define PACK2_BLKS 32
#define DEG_BLKS  6250
__global__ __launch_bounds__(256) void prep_k(const float4* __restrict__ x,
                                              uint4* __restrict__ xb,
                                              const float* __restrict__ W1,
                                              ushort* __restrict__ Wt,
                                              const float* __restrict__ W2,
                                              ushort* __restrict__ W2tb,
                                              const int* __restrict__ ei,
                                              int* __restrict__ deg) {
    int b = blockIdx.x;
    if (b < CAST_BLKS) {
        size_t i = (size_t)b * 256 + threadIdx.x;
        float4 a = x[2 * i], c = x[2 * i + 1];
        uint4 o;
        o.x = packbf2(a.x, a.y);
        o.y = packbf2(a.z, a.w);
        o.z = packbf2(c.x, c.y);
        o.w = packbf2(c.z, c.w);
        xb[i] = o;
    } else if (b < CAST_BLKS + PACK_BLKS) {
        int i = (b - CAST_BLKS) * 256 + threadIdx.x;
        int c = i >> 9, k = i & 511;
        int head = c >> 6, hid = c & 63;
        Wt[i] = f2bf(W1[(head * 512 + k) * 64 + hid]);
    } else if (b < CAST_BLKS + PACK_BLKS + PACK2_BLKS) {
        int i = (b - CAST_BLKS - PACK_BLKS) * 256 + threadIdx.x;   // i = c*512 + f
        int c = i >> 9, f = i & 511;
        W2tb[i] = f2bf(W2[f * 16 + c]);
    } else {
        int e = (b - CAST_BLKS - PACK_BLKS - PACK2_BLKS) * 256 + threadIdx.x;
        if (e < NE) atomicAdd(&deg[ei[e]], 1);
    }
}

// ---------------- parallel exclusive scan of deg -> rowptr (2 kernels) ----------------
#define SCAN_BLKS 196
__global__ __launch_bounds__(256) void scanA_k(const int* __restrict__ deg,
                                               int* __restrict__ rowptr,
                                               int* __restrict__ bsum) {
    __shared__ int wsum[4];
    const int t = threadIdx.x, lane = t & 63, wv = t >> 6;
    int i = blockIdx.x * 256 + t;
    int v = (i < NN) ? deg[i] : 0;
    int s = v;
#pragma unroll
    for (int o = 1; o < 64; o <<= 1) {
        int u = __shfl_up(s, o);
        if (lane >= o) s += u;
    }
    if (lane == 63) wsum[wv] = s;
    __syncthreads();
    if (t == 0) { wsum[1] += wsum[0]; wsum[2] += wsum[1]; wsum[3] += wsum[2]; }
    __syncthreads();
    int excl = s - v + (wv > 0 ? wsum[wv - 1] : 0);
    if (i < NN) rowptr[i] = excl;
    if (t == 255) bsum[blockIdx.x] = wsum[3];
}

__global__ __launch_bounds__(256) void scanBC_k(int* __restrict__ rowptr,
                                                const int* __restrict__ bsum) {
    __shared__ int ws[4];
    const int t = threadIdx.x, lane = t & 63, wv = t >> 6;
    int v = (t < SCAN_BLKS && t < (int)blockIdx.x) ? bsum[t] : 0;
#pragma unroll
    for (int o = 1; o < 64; o <<= 1) v += __shfl_xor(v, o);
    if (lane == 0) ws[wv] = v;
    __syncthreads();
    int tot = ws[0] + ws[1] + ws[2] + ws[3];
    int i = blockIdx.x * 256 + t;
    if (i < NN) rowptr[i] += tot;
    if (i == 0) rowptr[NN] = NE;
}

__global__ __launch_bounds__(256) void scatter_k(const int* __restrict__ ei,
                                                 const int* __restrict__ rowptr,
                                                 int* __restrict__ cursor,
                                                 ushort* __restrict__ csru) {
    int e = blockIdx.x * 256 + threadIdx.x;
    if (e < NE) {
        int src = ei[e];
        int pos = rowptr[src] + atomicAdd(&cursor[src], 1);
        csru[pos] = (ushort)ei[NE + e];
    }
}

// ---------------- GEMM1 (bf16 MFMA) 128x128 tile (2 heads) + fused scores ----------------
__global__ __launch_bounds__(256) void gemm1_k(const ushort* __restrict__ xb,
                                               const ushort* __restrict__ Wt,
                                               const float* __restrict__ a1,
                                               ushort* __restrict__ h1b,
                                               float* __restrict__ s1s,
                                               float* __restrict__ s1d) {
    __shared__ ushort As[128 * 32];   // [m][k]
    __shared__ ushort Bs[128 * 32];   // [c][k]
    const int tid = threadIdx.x;
    const int wv = tid >> 6, lane = tid & 63;
    const int quad = lane >> 4, l16 = lane & 15;
    const int row0 = blockIdx.y * 128;
    const int col0 = blockIdx.x * 128;
    const int sm = tid >> 2, sk = (tid & 3) * 8;
    floatx4 acc[2][8];
#pragma unroll
    for (int rt = 0; rt < 2; rt++)
#pragma unroll
        for (int ct = 0; ct < 8; ct++) acc[rt][ct] = (floatx4){0.f, 0.f, 0.f, 0.f};

    for (int k0 = 0; k0 < 512; k0 += 32) {
#pragma unroll
        for (int p = 0; p < 2; p++) {
            int r = row0 + sm + p * 64;
            uint4 av = make_uint4(0u, 0u, 0u, 0u);
            if (r < NN) av = *(const uint4*)(xb + (size_t)r * 512 + k0 + sk);
            *(uint4*)(As + (sm + p * 64) * 32 + sk) = av;
            int c = col0 + sm + p * 64;
            uint4 bv = *(const uint4*)(Wt + (size_t)c * 512 + k0 + sk);
            *(uint4*)(Bs + (sm + p * 64) * 32 + sk) = bv;
        }
        __syncthreads();
        short8 a0 = *(const short8*)(As + (wv * 32 + l16) * 32 + quad * 8);
        short8 a1f = *(const short8*)(As + (wv * 32 + 16 + l16) * 32 + quad * 8);
#pragma unroll
        for (int ct = 0; ct < 8; ct++) {
            short8 bf = *(const short8*)(Bs + (ct * 16 + l16) * 32 + quad * 8);
            acc[0][ct] = __builtin_amdgcn_mfma_f32_16x16x32_bf16(a0, bf, acc[0][ct], 0, 0, 0);
            acc[1][ct] = __builtin_amdgcn_mfma_f32_16x16x32_bf16(a1f, bf, acc[1][ct], 0, 0, 0);
        }
        __syncthreads();
    }

#pragma unroll
    for (int rt = 0; rt < 2; rt++) {
        const int rbase = row0 + wv * 32 + rt * 16 + quad * 4;
        float ss[2][4] = {}, sd[2][4] = {};
#pragma unroll
        for (int ct = 0; ct < 8; ct++) {
            int colg = col0 + ct * 16 + l16;
            int head = colg >> 6;
            int hh = ct >> 2;
            float avs = a1[head * 128 + (colg & 63)];
            float avd = a1[head * 128 + 64 + (colg & 63)];
#pragma unroll
            for (int r = 0; r < 4; r++) {
                float v = acc[rt][ct][r];
                ss[hh][r] += v * avs;
                sd[hh][r] += v * avd;
                int row = rbase + r;
                if (row < NN) h1b[(size_t)row * 512 + colg] = f2bf(v);
            }
        }
#pragma unroll
        for (int hh = 0; hh < 2; hh++)
#pragma unroll
            for (int r = 0; r < 4; r++) {
                float a_ = ss[hh][r], b_ = sd[hh][r];
#pragma unroll
                for (int o = 1; o < 16; o <<= 1) {
                    a_ += __shfl_xor(a_, o);
                    b_ += __shfl_xor(b_, o);
                }
                int row = rbase + r;
                if (l16 == 0 && row < NN) {
                    int head = (col0 >> 6) + hh;
                    s1s[head * NN + row] = a_;
                    s1d[head * NN + row] = b_;
                }
            }
    }
}

// ---------------- fused layer-1 aggregation (16/8-edge batch) + GEMM2 + scores ----------------
__global__ __launch_bounds__(256) void agg1f_k(const int* __restrict__ rowptr,
                                               const ushort* __restrict__ csru,
                                               const float* __restrict__ s1s,
                                               const float* __restrict__ s1d,
                                               const uint4* __restrict__ hb,
                                               const ushort* __restrict__ W2tb,
                                               const float* __restrict__ a2,
                                               float* __restrict__ h2,
                                               float* __restrict__ s2s,
                                               float* __restrict__ s2d) {
    __shared__ ushort Ash[16 * 512];
    const int tid = threadIdx.x;
    const int wv = tid >> 6, lane = tid & 63;
    const int n0 = blockIdx.x * 4;
    const int n = n0 + wv;              // NN % 4 == 0
    const int head8 = lane >> 3;
    const int esub = lane & 7;
    const int beg = rowptr[n];
    const int deg = rowptr[n + 1] - beg;
    const float ssrc = s1s[head8 * NN + n];
    float acc[8] = {};
    float rsum = 0.f;

    int k = 0;
    for (; k + 16 <= deg; k += 16) {
        // 16 edges in flight: lane handles edges k+esub and k+8+esub for head8
        int dA = csru[beg + k + esub];
        int dB = csru[beg + k + 8 + esub];
        float wA = edge_w(ssrc + s1d[head8 * NN + dA]);
        float wB = edge_w(ssrc + s1d[head8 * NN + dB]);
        rsum += wA + wB;
        int dj[16];
#pragma unroll
        for (int j = 0; j < 8; j++) { dj[j] = __shfl(dA, j); dj[8 + j] = __shfl(dB, j); }
        uint4 v[16];
#pragma unroll
        for (int j = 0; j < 16; j++) v[j] = hb[(size_t)dj[j] * 64 + lane];
#pragma unroll
        for (int j = 0; j < 16; j++) {
            float wj = __shfl(j < 8 ? wA : wB, (head8 << 3) + (j & 7));
            acc[0] += wj * bflo(v[j].x); acc[1] += wj * bfhi(v[j].x);
            acc[2] += wj * bflo(v[j].y); acc[3] += wj * bfhi(v[j].y);
            acc[4] += wj * bflo(v[j].z); acc[5] += wj * bfhi(v[j].z);
            acc[6] += wj * bflo(v[j].w); acc[7] += wj * bfhi(v[j].w);
        }
    }
    for (; k + 8 <= deg; k += 8) {
        int dA = csru[beg + k + esub];
        float wA = edge_w(ssrc + s1d[head8 * NN + dA]);
        rsum += wA;
        int dj[8];
#pragma unroll
        for (int j = 0; j < 8; j++) dj[j] = __shfl(dA, j);
        uint4 v[8];
#pragma unroll
        for (int j = 0; j < 8; j++) v[j] = hb[(size_t)dj[j] * 64 + lane];
#pragma unroll
        for (int j = 0; j < 8; j++) {
            float wj = __shfl(wA, (head8 << 3) + j);
            acc[0] += wj * bflo(v[j].x); acc[1] += wj * bfhi(v[j].x);
            acc[2] += wj * bflo(v[j].y); acc[3] += wj * bfhi(v[j].y);
            acc[4] += wj * bflo(v[j].z); acc[5] += wj * bfhi(v[j].z);
            acc[6] += wj * bflo(v[j].w); acc[7] += wj * bfhi(v[j].w);
        }
    }
    if (k < deg) {                       // rem in [1,7]
        int jc = min(k + esub, deg - 1);
        int dwj = csru[beg + jc];
        float w = edge_w(ssrc + s1d[head8 * NN + dwj]);
        if (k + esub >= deg) w = 0.f;
        rsum += w;
        int rem = deg - k;
        for (int j = 0; j < rem; j++) {
            int djs = __shfl(dwj, j);
            uint4 vv = hb[(size_t)djs * 64 + lane];
            float wj = __shfl(w, (head8 << 3) + j);
            acc[0] += wj * bflo(vv.x); acc[1] += wj * bfhi(vv.x);
            acc[2] += wj * bflo(vv.y); acc[3] += wj * bfhi(vv.y);
            acc[4] += wj * bflo(vv.z); acc[5] += wj * bfhi(vv.z);
            acc[6] += wj * bflo(vv.w); acc[7] += wj * bfhi(vv.w);
        }
    }

    rsum += __shfl_xor(rsum, 1);
    rsum += __shfl_xor(rsum, 2);
    rsum += __shfl_xor(rsum, 4);
    float inv = 1.0f / rsum;
    uint4 o;
    o.x = packbf2(elu_f(acc[0] * inv), elu_f(acc[1] * inv));
    o.y = packbf2(elu_f(acc[2] * inv), elu_f(acc[3] * inv));
    o.z = packbf2(elu_f(acc[4] * inv), elu_f(acc[5] * inv));
    o.w = packbf2(elu_f(acc[6] * inv), elu_f(acc[7] * inv));
    *(uint4*)(Ash + wv * 512 + lane * 8) = o;
    __syncthreads();

    if (wv == 0) {
        const int l16 = lane & 15, q = lane >> 4;
        floatx4 c2 = (floatx4){0.f, 0.f, 0.f, 0.f};
#pragma unroll
        for (int s = 0; s < 16; s++) {
            short8 af = *(const short8*)(Ash + l16 * 512 + s * 32 + q * 8);
            short8 bf = *(const short8*)(W2tb + l16 * 512 + s * 32 + q * 8);
            c2 = __builtin_amdgcn_mfma_f32_16x16x32_bf16(af, bf, c2, 0, 0, 0);
        }
        if (q == 0) {
#pragma unroll
            for (int r = 0; r < 4; r++) h2[(size_t)(n0 + r) * 16 + l16] = c2[r];
        }
#pragma unroll
        for (int r = 0; r < 4; r++) {
            float ssv = c2[r] * a2[l16];
            float sdv = c2[r] * a2[16 + l16];
#pragma unroll
            for (int oo = 1; oo < 16; oo <<= 1) {
                ssv += __shfl_xor(ssv, oo);
                sdv += __shfl_xor(sdv, oo);
            }
            if (lane == 0) { s2s[n0 + r] = ssv; s2d[n0 + r] = sdv; }
        }
    }
}

// ---------------- layer-2 aggregation + fused log_softmax ----------------
__global__ __launch_bounds__(256) void agg2_k(const int* __restrict__ rowptr,
                                              const ushort* __restrict__ csru,
                                              const float* __restrict__ s2s,
                                              const float* __restrict__ s2d,
                                              const float* __restrict__ h2,
                                              float* __restrict__ out) {
    const int n = (blockIdx.x * 256 + threadIdx.x) >> 6;
    const int lane = threadIdx.x & 63;
    if (n >= NN) return;
    const int beg = rowptr[n], end = rowptr[n + 1];
    const float sn = s2s[n];
    const int sub = lane >> 4, f = lane & 15;
    float acc = 0.f, rsum = 0.f;
    int e = beg + sub;
    for (; e + 4 < end; e += 8) {
        int d0 = csru[e], d1 = csru[e + 4];
        float t0 = s2d[d0], t1 = s2d[d1];
        float h0 = h2[(size_t)d0 * 16 + f], h1v = h2[(size_t)d1 * 16 + f];
        float w0 = edge_w(sn + t0), w1 = edge_w(sn + t1);
        acc += w0 * h0 + w1 * h1v;
        rsum += w0 + w1;
    }
    if (e < end) {
        int d0 = csru[e];
        float w0 = edge_w(sn + s2d[d0]);
        acc += w0 * h2[(size_t)d0 * 16 + f];
        rsum += w0;
    }
    acc += __shfl_down(acc, 32);
    acc += __shfl_down(acc, 16);
    rsum += __shfl_down(rsum, 32);
    rsum += __shfl_down(rsum, 16);
    if (lane < 16) {
        float v = elu_f(acc / rsum);
        float m = v;
#pragma unroll
        for (int o = 8; o > 0; o >>= 1) m = fmaxf(m, __shfl_xor(m, o));
        float ex = expf(v - m), s = ex;
#pragma unroll
        for (int o = 8; o > 0; o >>= 1) s += __shfl_xor(s, o);
        out[(size_t)n * 16 + f] = v - (logf(s) + m);
    }
}

extern "C" void kernel_launch(void* const* d_in, const int* in_sizes, int n_in,
                              void* d_out, int out_size, void* d_ws, size_t ws_size,
                              hipStream_t stream) {
    const float* x  = (const float*)d_in[0];
    const int*   ei = (const int*)d_in[1];
    const float* W1 = (const float*)d_in[2];
    const float* a1 = (const float*)d_in[3];
    const float* W2 = (const float*)d_in[4];
    const float* a2 = (const float*)d_in[5];
    float* out = (float*)d_out;

    ushort* xb    = (ushort*)d_ws;                 // 25.6M ushort
    ushort* h1b   = xb + (size_t)NN * 512;         // 25.6M
    ushort* Wt    = h1b + (size_t)NN * 512;        // 262144
    ushort* W2tb  = Wt + 512 * 512;                // 8192
    float* s1s    = (float*)(W2tb + 8192);         // 400K floats
    float* s1d    = s1s + (size_t)NN * H1;         // 400K
    int* deg      = (int*)(s1d + (size_t)NN * H1); // 50000
    int* cursor   = deg + NN;                      // 50000
    int* rowptr   = cursor + NN;                   // 50001
    int* bsum     = rowptr + NN + 1;               // 196 (+pad)
    ushort* csru  = (ushort*)(bsum + 256);         // 1.6M ushort
    float* h2     = (float*)(csru + NE);           // 800K floats
    float* s2s    = h2 + (size_t)NN * 16;          // 50000
    float* s2d    = s2s + NN;                      // 50000

    hipMemsetAsync(deg, 0, 2 * NN * sizeof(int), stream);  // deg + cursor

    prep_k<<<CAST_BLKS + PACK_BLKS + PACK2_BLKS + DEG_BLKS, 256, 0, stream>>>(
        (const float4*)x, (uint4*)xb, W1, Wt, W2, W2tb, ei, deg);
    scanA_k<<<SCAN_BLKS, 256, 0, stream>>>(deg, rowptr, bsum);
    scanBC_k<<<SCAN_BLKS, 256, 0, stream>>>(rowptr, bsum);
    scatter_k<<<(NE + 255) / 256, 256, 0, stream>>>(ei, rowptr, cursor, csru);
    gemm1_k<<<dim3(4, 391), 256, 0, stream>>>(xb, Wt, a1, h1b, s1s, s1d);
    agg1f_k<<<NN / 4, 256, 0, stream>>>(rowptr, csru, s1s, s1d,
                                        (const uint4*)h1b, W2tb, a2, h2, s2s, s2d);
    agg2_k<<<(NN + 3) / 4, 256, 0, stream>>>(rowptr, csru, s2s, s2d, h2, out);
}

// Round 11
// 562.361 us; speedup vs baseline: 1.3038x; 1.2185x over previous
//
#include <hip/hip_runtime.h>

#define NN 50000
#define NE 1600000
#define NFEAT 512
#define NHID 64
#define H1 8
#define NCLASS 16
#define ALPHA 0.2f

typedef __attribute__((ext_vector_type(8))) short short8;
typedef __attribute__((ext_vector_type(4))) float floatx4;
typedef __attribute__((ext_vector_type(2))) float floatx2;

__device__ __forceinline__ float elu_f(float x) { return x > 0.0f ? x : expf(x) - 1.0f; }
__device__ __forceinline__ float edge_w(float logit) {
    return expf(-fmaxf(logit, ALPHA * logit));   // exp(-leaky_relu)
}
__device__ __forceinline__ ushort f2bf(float f) {
    uint u = __float_as_uint(f);
    return (ushort)((u + 0x7FFFu + ((u >> 16) & 1)) >> 16);   // RNE
}
__device__ __forceinline__ uint packbf2(float lo, float hi) {
    return (uint)f2bf(lo) | ((uint)f2bf(hi) << 16);
}
__device__ __forceinline__ float bflo(uint v) { return __uint_as_float(v << 16); }
__device__ __forceinline__ float bfhi(uint v) { return __uint_as_float(v & 0xFFFF0000u); }
__device__ __forceinline__ unsigned char f2fp8(float v) {
    return (unsigned char)(__builtin_amdgcn_cvt_pk_fp8_f32(v, v, 0, false) & 0xFF);
}

// ------- phase 0 merged: cast x->bf16 | pack W1 | pack W2^T | degree hist -------
#define CAST_BLKS 12500
#define PACK_BLKS 1024
#define PACK2_BLKS 32
#define DEG_BLKS  6250
__global__ __launch_bounds__(256) void prep_k(const float4* __restrict__ x,
                                              uint4* __restrict__ xb,
                                              const float* __restrict__ W1,
                                              ushort* __restrict__ Wt,
                                              const float* __restrict__ W2,
                                              ushort* __restrict__ W2tb,
                                              const int* __restrict__ ei,
                                              int* __restrict__ deg) {
    int b = blockIdx.x;
    if (b < CAST_BLKS) {
        size_t i = (size_t)b * 256 + threadIdx.x;
        float4 a = x[2 * i], c = x[2 * i + 1];
        uint4 o;
        o.x = packbf2(a.x, a.y);
        o.y = packbf2(a.z, a.w);
        o.z = packbf2(c.x, c.y);
        o.w = packbf2(c.z, c.w);
        xb[i] = o;
    } else if (b < CAST_BLKS + PACK_BLKS) {
        int i = (b - CAST_BLKS) * 256 + threadIdx.x;
        int c = i >> 9, k = i & 511;
        int head = c >> 6, hid = c & 63;
        Wt[i] = f2bf(W1[(head * 512 + k) * 64 + hid]);
    } else if (b < CAST_BLKS + PACK_BLKS + PACK2_BLKS) {
        int i = (b - CAST_BLKS - PACK_BLKS) * 256 + threadIdx.x;   // i = c*512 + f
        int c = i >> 9, f = i & 511;
        W2tb[i] = f2bf(W2[f * 16 + c]);
    } else {
        int e = (b - CAST_BLKS - PACK_BLKS - PACK2_BLKS) * 256 + threadIdx.x;
        if (e < NE) atomicAdd(&deg[ei[e]], 1);
    }
}

// ---------------- parallel exclusive scan of deg -> rowptr (2 kernels) ----------------
#define SCAN_BLKS 196
__global__ __launch_bounds__(256) void scanA_k(const int* __restrict__ deg,
                                               int* __restrict__ rowptr,
                                               int* __restrict__ bsum) {
    __shared__ int wsum[4];
    const int t = threadIdx.x, lane = t & 63, wv = t >> 6;
    int i = blockIdx.x * 256 + t;
    int v = (i < NN) ? deg[i] : 0;
    int s = v;
#pragma unroll
    for (int o = 1; o < 64; o <<= 1) {
        int u = __shfl_up(s, o);
        if (lane >= o) s += u;
    }
    if (lane == 63) wsum[wv] = s;
    __syncthreads();
    if (t == 0) { wsum[1] += wsum[0]; wsum[2] += wsum[1]; wsum[3] += wsum[2]; }
    __syncthreads();
    int excl = s - v + (wv > 0 ? wsum[wv - 1] : 0);
    if (i < NN) rowptr[i] = excl;
    if (t == 255) bsum[blockIdx.x] = wsum[3];
}

__global__ __launch_bounds__(256) void scanBC_k(int* __restrict__ rowptr,
                                                const int* __restrict__ bsum) {
    __shared__ int ws[4];
    const int t = threadIdx.x, lane = t & 63, wv = t >> 6;
    int v = (t < SCAN_BLKS && t < (int)blockIdx.x) ? bsum[t] : 0;
#pragma unroll
    for (int o = 1; o < 64; o <<= 1) v += __shfl_xor(v, o);
    if (lane == 0) ws[wv] = v;
    __syncthreads();
    int tot = ws[0] + ws[1] + ws[2] + ws[3];
    int i = blockIdx.x * 256 + t;
    if (i < NN) rowptr[i] += tot;
    if (i == 0) rowptr[NN] = NE;
}

__global__ __launch_bounds__(256) void scatter_k(const int* __restrict__ ei,
                                                 const int* __restrict__ rowptr,
                                                 int* __restrict__ cursor,
                                                 ushort* __restrict__ csru) {
    int e = blockIdx.x * 256 + threadIdx.x;
    if (e < NE) {
        int src = ei[e];
        int pos = rowptr[src] + atomicAdd(&cursor[src], 1);
        csru[pos] = (ushort)ei[NE + e];
    }
}

// ---------------- GEMM1 (bf16 MFMA) 128x128 tile + fused scores, fp8 h1 output ----------------
__global__ __launch_bounds__(256) void gemm1_k(const ushort* __restrict__ xb,
                                               const ushort* __restrict__ Wt,
                                               const float* __restrict__ a1,
                                               unsigned char* __restrict__ h8,
                                               float* __restrict__ s1s,
                                               float* __restrict__ s1d) {
    __shared__ ushort As[128 * 32];   // [m][k]
    __shared__ ushort Bs[128 * 32];   // [c][k]
    const int tid = threadIdx.x;
    const int wv = tid >> 6, lane = tid & 63;
    const int quad = lane >> 4, l16 = lane & 15;
    const int row0 = blockIdx.y * 128;
    const int col0 = blockIdx.x * 128;
    const int sm = tid >> 2, sk = (tid & 3) * 8;
    floatx4 acc[2][8];
#pragma unroll
    for (int rt = 0; rt < 2; rt++)
#pragma unroll
        for (int ct = 0; ct < 8; ct++) acc[rt][ct] = (floatx4){0.f, 0.f, 0.f, 0.f};

    for (int k0 = 0; k0 < 512; k0 += 32) {
#pragma unroll
        for (int p = 0; p < 2; p++) {
            int r = row0 + sm + p * 64;
            uint4 av = make_uint4(0u, 0u, 0u, 0u);
            if (r < NN) av = *(const uint4*)(xb + (size_t)r * 512 + k0 + sk);
            *(uint4*)(As + (sm + p * 64) * 32 + sk) = av;
            int c = col0 + sm + p * 64;
            uint4 bv = *(const uint4*)(Wt + (size_t)c * 512 + k0 + sk);
            *(uint4*)(Bs + (sm + p * 64) * 32 + sk) = bv;
        }
        __syncthreads();
        short8 a0 = *(const short8*)(As + (wv * 32 + l16) * 32 + quad * 8);
        short8 a1f = *(const short8*)(As + (wv * 32 + 16 + l16) * 32 + quad * 8);
#pragma unroll
        for (int ct = 0; ct < 8; ct++) {
            short8 bf = *(const short8*)(Bs + (ct * 16 + l16) * 32 + quad * 8);
            acc[0][ct] = __builtin_amdgcn_mfma_f32_16x16x32_bf16(a0, bf, acc[0][ct], 0, 0, 0);
            acc[1][ct] = __builtin_amdgcn_mfma_f32_16x16x32_bf16(a1f, bf, acc[1][ct], 0, 0, 0);
        }
        __syncthreads();
    }

#pragma unroll
    for (int rt = 0; rt < 2; rt++) {
        const int rbase = row0 + wv * 32 + rt * 16 + quad * 4;
        float ss[2][4] = {}, sd[2][4] = {};
#pragma unroll
        for (int ct = 0; ct < 8; ct++) {
            int colg = col0 + ct * 16 + l16;
            int head = colg >> 6;
            int hh = ct >> 2;
            float avs = a1[head * 128 + (colg & 63)];
            float avd = a1[head * 128 + 64 + (colg & 63)];
#pragma unroll
            for (int r = 0; r < 4; r++) {
                float v = acc[rt][ct][r];
                ss[hh][r] += v * avs;
                sd[hh][r] += v * avd;
                int row = rbase + r;
                if (row < NN) h8[(size_t)row * 512 + colg] = f2fp8(v);
            }
        }
#pragma unroll
        for (int hh = 0; hh < 2; hh++)
#pragma unroll
            for (int r = 0; r < 4; r++) {
                float a_ = ss[hh][r], b_ = sd[hh][r];
#pragma unroll
                for (int o = 1; o < 16; o <<= 1) {
                    a_ += __shfl_xor(a_, o);
                    b_ += __shfl_xor(b_, o);
                }
                int row = rbase + r;
                if (l16 == 0 && row < NN) {
                    int head = (col0 >> 6) + hh;
                    s1s[head * NN + row] = a_;
                    s1d[head * NN + row] = b_;
                }
            }
    }
}

// ------- fused layer-1 aggregation (fp8 gather, 8-edge batch) + GEMM2 + scores -------
__global__ __launch_bounds__(256) void agg1f_k(const int* __restrict__ rowptr,
                                               const ushort* __restrict__ csru,
                                               const float* __restrict__ s1s,
                                               const float* __restrict__ s1d,
                                               const uint2* __restrict__ hb8,
                                               const ushort* __restrict__ W2tb,
                                               const float* __restrict__ a2,
                                               float* __restrict__ h2,
                                               float* __restrict__ s2s,
                                               float* __restrict__ s2d) {
    __shared__ ushort Ash[16 * 512];
    const int tid = threadIdx.x;
    const int wv = tid >> 6, lane = tid & 63;
    const int n0 = blockIdx.x * 4;
    const int n = n0 + wv;              // NN % 4 == 0
    const int head8 = lane >> 3;
    const int esub = lane & 7;
    const int beg = rowptr[n];
    const int deg = rowptr[n + 1] - beg;
    const float ssrc = s1s[head8 * NN + n];
    float acc[8] = {};
    float rsum = 0.f;

    int k = 0;
    for (; k + 8 <= deg; k += 8) {
        int dA = csru[beg + k + esub];
        float wA = edge_w(ssrc + s1d[head8 * NN + dA]);
        rsum += wA;
        int dj[8];
#pragma unroll
        for (int j = 0; j < 8; j++) dj[j] = __shfl(dA, j);
        uint2 v[8];
#pragma unroll
        for (int j = 0; j < 8; j++) v[j] = hb8[(size_t)dj[j] * 64 + lane];
#pragma unroll
        for (int j = 0; j < 8; j++) {
            float wj = __shfl(wA, (head8 << 3) + j);
            floatx2 p0 = __builtin_amdgcn_cvt_pk_f32_fp8(v[j].x, false);
            floatx2 p1 = __builtin_amdgcn_cvt_pk_f32_fp8(v[j].x, true);
            floatx2 p2 = __builtin_amdgcn_cvt_pk_f32_fp8(v[j].y, false);
            floatx2 p3 = __builtin_amdgcn_cvt_pk_f32_fp8(v[j].y, true);
            acc[0] += wj * p0[0]; acc[1] += wj * p0[1];
            acc[2] += wj * p1[0]; acc[3] += wj * p1[1];
            acc[4] += wj * p2[0]; acc[5] += wj * p2[1];
            acc[6] += wj * p3[0]; acc[7] += wj * p3[1];
        }
    }
    if (k < deg) {                       // rem in [1,7]
        int jc = min(k + esub, deg - 1);
        int dwj = csru[beg + jc];
        float w = edge_w(ssrc + s1d[head8 * NN + dwj]);
        if (k + esub >= deg) w = 0.f;
        rsum += w;
        int rem = deg - k;
        for (int j = 0; j < rem; j++) {
            int djs = __shfl(dwj, j);
            uint2 vv = hb8[(size_t)djs * 64 + lane];
            float wj = __shfl(w, (head8 << 3) + j);
            floatx2 p0 = __builtin_amdgcn_cvt_pk_f32_fp8(vv.x, false);
            floatx2 p1 = __builtin_amdgcn_cvt_pk_f32_fp8(vv.x, true);
            floatx2 p2 = __builtin_amdgcn_cvt_pk_f32_fp8(vv.y, false);
            floatx2 p3 = __builtin_amdgcn_cvt_pk_f32_fp8(vv.y, true);
            acc[0] += wj * p0[0]; acc[1] += wj * p0[1];
            acc[2] += wj * p1[0]; acc[3] += wj * p1[1];
            acc[4] += wj * p2[0]; acc[5] += wj * p2[1];
            acc[6] += wj * p3[0]; acc[7] += wj * p3[1];
        }
    }

    rsum += __shfl_xor(rsum, 1);
    rsum += __shfl_xor(rsum, 2);
    rsum += __shfl_xor(rsum, 4);
    float inv = 1.0f / rsum;
    uint4 o;
    o.x = packbf2(elu_f(acc[0] * inv), elu_f(acc[1] * inv));
    o.y = packbf2(elu_f(acc[2] * inv), elu_f(acc[3] * inv));
    o.z = packbf2(elu_f(acc[4] * inv), elu_f(acc[5] * inv));
    o.w = packbf2(elu_f(acc[6] * inv), elu_f(acc[7] * inv));
    *(uint4*)(Ash + wv * 512 + lane * 8) = o;
    __syncthreads();

    if (wv == 0) {
        const int l16 = lane & 15, q = lane >> 4;
        floatx4 c2 = (floatx4){0.f, 0.f, 0.f, 0.f};
#pragma unroll
        for (int s = 0; s < 16; s++) {
            short8 af = *(const short8*)(Ash + l16 * 512 + s * 32 + q * 8);
            short8 bf = *(const short8*)(W2tb + l16 * 512 + s * 32 + q * 8);
            c2 = __builtin_amdgcn_mfma_f32_16x16x32_bf16(af, bf, c2, 0, 0, 0);
        }
        if (q == 0) {
#pragma unroll
            for (int r = 0; r < 4; r++) h2[(size_t)(n0 + r) * 16 + l16] = c2[r];
        }
#pragma unroll
        for (int r = 0; r < 4; r++) {
            float ssv = c2[r] * a2[l16];
            float sdv = c2[r] * a2[16 + l16];
#pragma unroll
            for (int oo = 1; oo < 16; oo <<= 1) {
                ssv += __shfl_xor(ssv, oo);
                sdv += __shfl_xor(sdv, oo);
            }
            if (lane == 0) { s2s[n0 + r] = ssv; s2d[n0 + r] = sdv; }
        }
    }
}

// ---------------- layer-2 aggregation + fused log_softmax ----------------
__global__ __launch_bounds__(256) void agg2_k(const int* __restrict__ rowptr,
                                              const ushort* __restrict__ csru,
                                              const float* __restrict__ s2s,
                                              const float* __restrict__ s2d,
                                              const float* __restrict__ h2,
                                              float* __restrict__ out) {
    const int n = (blockIdx.x * 256 + threadIdx.x) >> 6;
    const int lane = threadIdx.x & 63;
    if (n >= NN) return;
    const int beg = rowptr[n], end = rowptr[n + 1];
    const float sn = s2s[n];
    const int sub = lane >> 4, f = lane & 15;
    float acc = 0.f, rsum = 0.f;
    int e = beg + sub;
    for (; e + 4 < end; e += 8) {
        int d0 = csru[e], d1 = csru[e + 4];
        float t0 = s2d[d0], t1 = s2d[d1];
        float h0 = h2[(size_t)d0 * 16 + f], h1v = h2[(size_t)d1 * 16 + f];
        float w0 = edge_w(sn + t0), w1 = edge_w(sn + t1);
        acc += w0 * h0 + w1 * h1v;
        rsum += w0 + w1;
    }
    if (e < end) {
        int d0 = csru[e];
        float w0 = edge_w(sn + s2d[d0]);
        acc += w0 * h2[(size_t)d0 * 16 + f];
        rsum += w0;
    }
    acc += __shfl_down(acc, 32);
    acc += __shfl_down(acc, 16);
    rsum += __shfl_down(rsum, 32);
    rsum += __shfl_down(rsum, 16);
    if (lane < 16) {
        float v = elu_f(acc / rsum);
        float m = v;
#pragma unroll
        for (int o = 8; o > 0; o >>= 1) m = fmaxf(m, __shfl_xor(m, o));
        float ex = expf(v - m), s = ex;
#pragma unroll
        for (int o = 8; o > 0; o >>= 1) s += __shfl_xor(s, o);
        out[(size_t)n * 16 + f] = v - (logf(s) + m);
    }
}

extern "C" void kernel_launch(void* const* d_in, const int* in_sizes, int n_in,
                              void* d_out, int out_size, void* d_ws, size_t ws_size,
                              hipStream_t stream) {
    const float* x  = (const float*)d_in[0];
    const int*   ei = (const int*)d_in[1];
    const float* W1 = (const float*)d_in[2];
    const float* a1 = (const float*)d_in[3];
    const float* W2 = (const float*)d_in[4];
    const float* a2 = (const float*)d_in[5];
    float* out = (float*)d_out;

    ushort* xb        = (ushort*)d_ws;                   // 25.6M ushort
    unsigned char* h8 = (unsigned char*)(xb + (size_t)NN * 512);   // 25.6M bytes
    ushort* Wt    = (ushort*)(h8 + (size_t)NN * 512);    // 262144
    ushort* W2tb  = Wt + 512 * 512;                      // 8192
    float* s1s    = (float*)(W2tb + 8192);               // 400K floats
    float* s1d    = s1s + (size_t)NN * H1;               // 400K
    int* deg      = (int*)(s1d + (size_t)NN * H1);       // 50000
    int* cursor   = deg + NN;                            // 50000
    int* rowptr   = cursor + NN;                         // 50001
    int* bsum     = rowptr + NN + 1;                     // 196 (+pad)
    ushort* csru  = (ushort*)(bsum + 256);               // 1.6M ushort
    float* h2     = (float*)(csru + NE);                 // 800K floats
    float* s2s    = h2 + (size_t)NN * 16;                // 50000
    float* s2d    = s2s + NN;                            // 50000

    hipMemsetAsync(deg, 0, 2 * NN * sizeof(int), stream);  // deg + cursor

    prep_k<<<CAST_BLKS + PACK_BLKS + PACK2_BLKS + DEG_BLKS, 256, 0, stream>>>(
        (const float4*)x, (uint4*)xb, W1, Wt, W2, W2tb, ei, deg);
    scanA_k<<<SCAN_BLKS, 256, 0, stream>>>(deg, rowptr, bsum);
    scanBC_k<<<SCAN_BLKS, 256, 0, stream>>>(rowptr, bsum);
    scatter_k<<<(NE + 255) / 256, 256, 0, stream>>>(ei, rowptr, cursor, csru);
    gemm1_k<<<dim3(4, 391), 256, 0, stream>>>(xb, Wt, a1, h8, s1s, s1d);
    agg1f_k<<<NN / 4, 256, 0, stream>>>(rowptr, csru, s1s, s1d,
                                        (const uint2*)h8, W2tb, a2, h2, s2s, s2d);
    agg2_k<<<(NN + 3) / 4, 256, 0, stream>>>(rowptr, csru, s2s, s2d, h2, out);
}

// Round 12
// 553.585 us; speedup vs baseline: 1.3244x; 1.0159x over previous
//
#include <hip/hip_runtime.h>

#define NN 50000
#define NE 1600000
#define NFEAT 512
#define NHID 64
#define H1 8
#define NCLASS 16
#define ALPHA 0.2f

typedef __attribute__((ext_vector_type(8))) short short8;
typedef __attribute__((ext_vector_type(4))) float floatx4;
typedef __attribute__((ext_vector_type(2))) float floatx2;

__device__ __forceinline__ float elu_f(float x) { return x > 0.0f ? x : expf(x) - 1.0f; }
__device__ __forceinline__ float edge_w(float logit) {
    return expf(-fmaxf(logit, ALPHA * logit));   // exp(-leaky_relu)
}
__device__ __forceinline__ ushort f2bf(float f) {
    uint u = __float_as_uint(f);
    return (ushort)((u + 0x7FFFu + ((u >> 16) & 1)) >> 16);   // RNE
}
__device__ __forceinline__ uint packbf2(float lo, float hi) {
    return (uint)f2bf(lo) | ((uint)f2bf(hi) << 16);
}
__device__ __forceinline__ unsigned char f2fp8(float v) {
    return (unsigned char)(__builtin_amdgcn_cvt_pk_fp8_f32(v, v, 0, false) & 0xFF);
}
__device__ __forceinline__ uint pack4fp8(float a, float b, float c, float d) {
    uint u = __builtin_amdgcn_cvt_pk_fp8_f32(a, b, 0, false);
    return __builtin_amdgcn_cvt_pk_fp8_f32(c, d, u, true);
}

// ------- phase 0 merged: cast x->fp8 | pack W1 fp8 | pack W2^T bf16 | degree hist -------
#define CAST_BLKS 12500
#define PACK_BLKS 1024
#define PACK2_BLKS 32
#define DEG_BLKS  6250
__global__ __launch_bounds__(256) void prep_k(const float4* __restrict__ x,
                                              uint2* __restrict__ xb8,
                                              const float* __restrict__ W1,
                                              unsigned char* __restrict__ Wt8,
                                              const float* __restrict__ W2,
                                              ushort* __restrict__ W2tb,
                                              const int* __restrict__ ei,
                                              int* __restrict__ deg) {
    int b = blockIdx.x;
    if (b < CAST_BLKS) {
        size_t i = (size_t)b * 256 + threadIdx.x;    // 8 floats per thread
        float4 a = x[2 * i], c = x[2 * i + 1];
        uint2 o;
        o.x = pack4fp8(a.x, a.y, a.z, a.w);
        o.y = pack4fp8(c.x, c.y, c.z, c.w);
        xb8[i] = o;
    } else if (b < CAST_BLKS + PACK_BLKS) {
        int i = (b - CAST_BLKS) * 256 + threadIdx.x;   // i = c*512 + k
        int c = i >> 9, k = i & 511;
        int head = c >> 6, hid = c & 63;
        Wt8[i] = f2fp8(W1[(head * 512 + k) * 64 + hid]);
    } else if (b < CAST_BLKS + PACK_BLKS + PACK2_BLKS) {
        int i = (b - CAST_BLKS - PACK_BLKS) * 256 + threadIdx.x;   // i = c*512 + f
        int c = i >> 9, f = i & 511;
        W2tb[i] = f2bf(W2[f * 16 + c]);
    } else {
        int e = (b - CAST_BLKS - PACK_BLKS - PACK2_BLKS) * 256 + threadIdx.x;
        if (e < NE) atomicAdd(&deg[ei[e]], 1);
    }
}

// ---------------- parallel exclusive scan of deg -> rowptr (2 kernels) ----------------
#define SCAN_BLKS 196
__global__ __launch_bounds__(256) void scanA_k(const int* __restrict__ deg,
                                               int* __restrict__ rowptr,
                                               int* __restrict__ bsum) {
    __shared__ int wsum[4];
    const int t = threadIdx.x, lane = t & 63, wv = t >> 6;
    int i = blockIdx.x * 256 + t;
    int v = (i < NN) ? deg[i] : 0;
    int s = v;
#pragma unroll
    for (int o = 1; o < 64; o <<= 1) {
        int u = __shfl_up(s, o);
        if (lane >= o) s += u;
    }
    if (lane == 63) wsum[wv] = s;
    __syncthreads();
    if (t == 0) { wsum[1] += wsum[0]; wsum[2] += wsum[1]; wsum[3] += wsum[2]; }
    __syncthreads();
    int excl = s - v + (wv > 0 ? wsum[wv - 1] : 0);
    if (i < NN) rowptr[i] = excl;
    if (t == 255) bsum[blockIdx.x] = wsum[3];
}

__global__ __launch_bounds__(256) void scanBC_k(int* __restrict__ rowptr,
                                                const int* __restrict__ bsum) {
    __shared__ int ws[4];
    const int t = threadIdx.x, lane = t & 63, wv = t >> 6;
    int v = (t < SCAN_BLKS && t < (int)blockIdx.x) ? bsum[t] : 0;
#pragma unroll
    for (int o = 1; o < 64; o <<= 1) v += __shfl_xor(v, o);
    if (lane == 0) ws[wv] = v;
    __syncthreads();
    int tot = ws[0] + ws[1] + ws[2] + ws[3];
    int i = blockIdx.x * 256 + t;
    if (i < NN) rowptr[i] += tot;
    if (i == 0) rowptr[NN] = NE;
}

__global__ __launch_bounds__(256) void scatter_k(const int* __restrict__ ei,
                                                 const int* __restrict__ rowptr,
                                                 int* __restrict__ cursor,
                                                 ushort* __restrict__ csru) {
    int e = blockIdx.x * 256 + threadIdx.x;
    if (e < NE) {
        int src = ei[e];
        int pos = rowptr[src] + atomicAdd(&cursor[src], 1);
        csru[pos] = (ushort)ei[NE + e];
    }
}

// ------- GEMM1 (fp8 MFMA) 128x128 tile + fused scores; h1 out fp8, scores [n][h] -------
__global__ __launch_bounds__(256) void gemm1_k(const unsigned char* __restrict__ xb8,
                                               const unsigned char* __restrict__ Wt8,
                                               const float* __restrict__ a1,
                                               unsigned char* __restrict__ h8,
                                               float* __restrict__ s1s,
                                               float* __restrict__ s1d) {
    __shared__ unsigned char As[128 * 32];   // [m][k] 4 KB
    __shared__ unsigned char Bs[128 * 32];   // [c][k] 4 KB
    const int tid = threadIdx.x;
    const int wv = tid >> 6, lane = tid & 63;
    const int quad = lane >> 4, l16 = lane & 15;
    const int row0 = blockIdx.y * 128;
    const int col0 = blockIdx.x * 128;
    const int sm = tid >> 2, sk = (tid & 3) * 8;   // 8 fp8 per thread per half
    floatx4 acc[2][8];
#pragma unroll
    for (int rt = 0; rt < 2; rt++)
#pragma unroll
        for (int ct = 0; ct < 8; ct++) acc[rt][ct] = (floatx4){0.f, 0.f, 0.f, 0.f};

    for (int k0 = 0; k0 < 512; k0 += 32) {
#pragma unroll
        for (int p = 0; p < 2; p++) {
            int r = row0 + sm + p * 64;
            uint2 av = make_uint2(0u, 0u);
            if (r < NN) av = *(const uint2*)(xb8 + (size_t)r * 512 + k0 + sk);
            *(uint2*)(As + (sm + p * 64) * 32 + sk) = av;
            int c = col0 + sm + p * 64;
            uint2 bv = *(const uint2*)(Wt8 + (size_t)c * 512 + k0 + sk);
            *(uint2*)(Bs + (sm + p * 64) * 32 + sk) = bv;
        }
        __syncthreads();
        long a0 = *(const long*)(As + (wv * 32 + l16) * 32 + quad * 8);
        long a1f = *(const long*)(As + (wv * 32 + 16 + l16) * 32 + quad * 8);
#pragma unroll
        for (int ct = 0; ct < 8; ct++) {
            long bf = *(const long*)(Bs + (ct * 16 + l16) * 32 + quad * 8);
            acc[0][ct] = __builtin_amdgcn_mfma_f32_16x16x32_fp8_fp8(a0, bf, acc[0][ct], 0, 0, 0);
            acc[1][ct] = __builtin_amdgcn_mfma_f32_16x16x32_fp8_fp8(a1f, bf, acc[1][ct], 0, 0, 0);
        }
        __syncthreads();
    }

#pragma unroll
    for (int rt = 0; rt < 2; rt++) {
        const int rbase = row0 + wv * 32 + rt * 16 + quad * 4;
        float ss[2][4] = {}, sd[2][4] = {};
#pragma unroll
        for (int ct = 0; ct < 8; ct++) {
            int colg = col0 + ct * 16 + l16;
            int head = colg >> 6;
            int hh = ct >> 2;
            float avs = a1[head * 128 + (colg & 63)];
            float avd = a1[head * 128 + 64 + (colg & 63)];
#pragma unroll
            for (int r = 0; r < 4; r++) {
                float v = acc[rt][ct][r];
                ss[hh][r] += v * avs;
                sd[hh][r] += v * avd;
                int row = rbase + r;
                if (row < NN) h8[(size_t)row * 512 + colg] = f2fp8(v);
            }
        }
#pragma unroll
        for (int hh = 0; hh < 2; hh++)
#pragma unroll
            for (int r = 0; r < 4; r++) {
                float a_ = ss[hh][r], b_ = sd[hh][r];
#pragma unroll
                for (int o = 1; o < 16; o <<= 1) {
                    a_ += __shfl_xor(a_, o);
                    b_ += __shfl_xor(b_, o);
                }
                int row = rbase + r;
                if (l16 == 0 && row < NN) {
                    int head = (col0 >> 6) + hh;
                    s1s[row * 8 + head] = a_;    // [node][head] layout
                    s1d[row * 8 + head] = b_;
                }
            }
    }
}

// ------- fused layer-1 aggregation (fp8 gather, packed fp32 acc) + GEMM2 + scores -------
__global__ __launch_bounds__(256) void agg1f_k(const int* __restrict__ rowptr,
                                               const ushort* __restrict__ csru,
                                               const float* __restrict__ s1s,
                                               const float* __restrict__ s1d,
                                               const uint2* __restrict__ hb8,
                                               const ushort* __restrict__ W2tb,
                                               const float* __restrict__ a2,
                                               float* __restrict__ h2,
                                               float* __restrict__ s2s,
                                               float* __restrict__ s2d) {
    __shared__ ushort Ash[16 * 512];
    const int tid = threadIdx.x;
    const int wv = tid >> 6, lane = tid & 63;
    const int n0 = blockIdx.x * 4;
    const int n = n0 + wv;              // NN % 4 == 0
    const int head8 = lane >> 3;
    const int esub = lane & 7;
    const int beg = rowptr[n];
    const int deg = rowptr[n + 1] - beg;
    const float ssrc = s1s[n * 8 + head8];
    floatx2 acc[4] = {};
    float rsum = 0.f;

    int k = 0;
    for (; k + 8 <= deg; k += 8) {
        int dA = csru[beg + k + esub];
        float wA = edge_w(ssrc + s1d[dA * 8 + head8]);   // 8 lanes share one 32B line
        rsum += wA;
        int dj[8];
#pragma unroll
        for (int j = 0; j < 8; j++) dj[j] = __shfl(dA, j);
        uint2 v[8];
#pragma unroll
        for (int j = 0; j < 8; j++) v[j] = hb8[(uint)dj[j] * 64 + lane];
#pragma unroll
        for (int j = 0; j < 8; j++) {
            float wj = __shfl(wA, (head8 << 3) + j);
            floatx2 w2 = (floatx2){wj, wj};
            acc[0] += w2 * __builtin_amdgcn_cvt_pk_f32_fp8(v[j].x, false);
            acc[1] += w2 * __builtin_amdgcn_cvt_pk_f32_fp8(v[j].x, true);
            acc[2] += w2 * __builtin_amdgcn_cvt_pk_f32_fp8(v[j].y, false);
            acc[3] += w2 * __builtin_amdgcn_cvt_pk_f32_fp8(v[j].y, true);
        }
    }
    if (k < deg) {                       // rem in [1,7]
        int jc = min(k + esub, deg - 1);
        int dwj = csru[beg + jc];
        float w = edge_w(ssrc + s1d[dwj * 8 + head8]);
        if (k + esub >= deg) w = 0.f;
        rsum += w;
        int rem = deg - k;
        for (int j = 0; j < rem; j++) {
            int djs = __shfl(dwj, j);
            uint2 vv = hb8[(uint)djs * 64 + lane];
            float wj = __shfl(w, (head8 << 3) + j);
            floatx2 w2 = (floatx2){wj, wj};
            acc[0] += w2 * __builtin_amdgcn_cvt_pk_f32_fp8(vv.x, false);
            acc[1] += w2 * __builtin_amdgcn_cvt_pk_f32_fp8(vv.x, true);
            acc[2] += w2 * __builtin_amdgcn_cvt_pk_f32_fp8(vv.y, false);
            acc[3] += w2 * __builtin_amdgcn_cvt_pk_f32_fp8(vv.y, true);
        }
    }

    rsum += __shfl_xor(rsum, 1);
    rsum += __shfl_xor(rsum, 2);
    rsum += __shfl_xor(rsum, 4);
    float inv = 1.0f / rsum;
    uint4 o;
    o.x = packbf2(elu_f(acc[0][0] * inv), elu_f(acc[0][1] * inv));
    o.y = packbf2(elu_f(acc[1][0] * inv), elu_f(acc[1][1] * inv));
    o.z = packbf2(elu_f(acc[2][0] * inv), elu_f(acc[2][1] * inv));
    o.w = packbf2(elu_f(acc[3][0] * inv), elu_f(acc[3][1] * inv));
    *(uint4*)(Ash + wv * 512 + lane * 8) = o;
    __syncthreads();

    if (wv == 0) {
        const int l16 = lane & 15, q = lane >> 4;
        floatx4 c2 = (floatx4){0.f, 0.f, 0.f, 0.f};
#pragma unroll
        for (int s = 0; s < 16; s++) {
            short8 af = *(const short8*)(Ash + l16 * 512 + s * 32 + q * 8);
            short8 bf = *(const short8*)(W2tb + l16 * 512 + s * 32 + q * 8);
            c2 = __builtin_amdgcn_mfma_f32_16x16x32_bf16(af, bf, c2, 0, 0, 0);
        }
        if (q == 0) {
#pragma unroll
            for (int r = 0; r < 4; r++) h2[(size_t)(n0 + r) * 16 + l16] = c2[r];
        }
#pragma unroll
        for (int r = 0; r < 4; r++) {
            float ssv = c2[r] * a2[l16];
            float sdv = c2[r] * a2[16 + l16];
#pragma unroll
            for (int oo = 1; oo < 16; oo <<= 1) {
                ssv += __shfl_xor(ssv, oo);
                sdv += __shfl_xor(sdv, oo);
            }
            if (lane == 0) { s2s[n0 + r] = ssv; s2d[n0 + r] = sdv; }
        }
    }
}

// ---------------- layer-2 aggregation + fused log_softmax ----------------
__global__ __launch_bounds__(256) void agg2_k(const int* __restrict__ rowptr,
                                              const ushort* __restrict__ csru,
                                              const float* __restrict__ s2s,
                                              const float* __restrict__ s2d,
                                              const float* __restrict__ h2,
                                              float* __restrict__ out) {
    const int n = (blockIdx.x * 256 + threadIdx.x) >> 6;
    const int lane = threadIdx.x & 63;
    if (n >= NN) return;
    const int beg = rowptr[n], end = rowptr[n + 1];
    const float sn = s2s[n];
    const int sub = lane >> 4, f = lane & 15;
    float acc = 0.f, rsum = 0.f;
    int e = beg + sub;
    for (; e + 4 < end; e += 8) {
        int d0 = csru[e], d1 = csru[e + 4];
        float t0 = s2d[d0], t1 = s2d[d1];
        float h0 = h2[(size_t)d0 * 16 + f], h1v = h2[(size_t)d1 * 16 + f];
        float w0 = edge_w(sn + t0), w1 = edge_w(sn + t1);
        acc += w0 * h0 + w1 * h1v;
        rsum += w0 + w1;
    }
    if (e < end) {
        int d0 = csru[e];
        float w0 = edge_w(sn + s2d[d0]);
        acc += w0 * h2[(size_t)d0 * 16 + f];
        rsum += w0;
    }
    acc += __shfl_down(acc, 32);
    acc += __shfl_down(acc, 16);
    rsum += __shfl_down(rsum, 32);
    rsum += __shfl_down(rsum, 16);
    if (lane < 16) {
        float v = elu_f(acc / rsum);
        float m = v;
#pragma unroll
        for (int o = 8; o > 0; o >>= 1) m = fmaxf(m, __shfl_xor(m, o));
        float ex = expf(v - m), s = ex;
#pragma unroll
        for (int o = 8; o > 0; o >>= 1) s += __shfl_xor(s, o);
        out[(size_t)n * 16 + f] = v - (logf(s) + m);
    }
}

extern "C" void kernel_launch(void* const* d_in, const int* in_sizes, int n_in,
                              void* d_out, int out_size, void* d_ws, size_t ws_size,
                              hipStream_t stream) {
    const float* x  = (const float*)d_in[0];
    const int*   ei = (const int*)d_in[1];
    const float* W1 = (const float*)d_in[2];
    const float* a1 = (const float*)d_in[3];
    const float* W2 = (const float*)d_in[4];
    const float* a2 = (const float*)d_in[5];
    float* out = (float*)d_out;

    unsigned char* xb8 = (unsigned char*)d_ws;           // 25.6M bytes
    unsigned char* h8  = xb8 + (size_t)NN * 512;         // 25.6M bytes
    unsigned char* Wt8 = h8 + (size_t)NN * 512;          // 262144 bytes
    ushort* W2tb  = (ushort*)(Wt8 + 512 * 512);          // 8192 ushorts
    float* s1s    = (float*)(W2tb + 8192);               // 400K floats [n][h]
    float* s1d    = s1s + (size_t)NN * H1;               // 400K
    int* deg      = (int*)(s1d + (size_t)NN * H1);       // 50000
    int* cursor   = deg + NN;                            // 50000
    int* rowptr   = cursor + NN;                         // 50001
    int* bsum     = rowptr + NN + 1;                     // 196 (+pad)
    ushort* csru  = (ushort*)(bsum + 256);               // 1.6M ushort
    float* h2     = (float*)(csru + NE);                 // 800K floats
    float* s2s    = h2 + (size_t)NN * 16;                // 50000
    float* s2d    = s2s + NN;                            // 50000

    hipMemsetAsync(deg, 0, 2 * NN * sizeof(int), stream);  // deg + cursor

    prep_k<<<CAST_BLKS + PACK_BLKS + PACK2_BLKS + DEG_BLKS, 256, 0, stream>>>(
        (const float4*)x, (uint2*)xb8, W1, Wt8, W2, W2tb, ei, deg);
    scanA_k<<<SCAN_BLKS, 256, 0, stream>>>(deg, rowptr, bsum);
    scanBC_k<<<SCAN_BLKS, 256, 0, stream>>>(rowptr, bsum);
    scatter_k<<<(NE + 255) / 256, 256, 0, stream>>>(ei, rowptr, cursor, csru);
    gemm1_k<<<dim3(4, 391), 256, 0, stream>>>(xb8, Wt8, a1, h8, s1s, s1d);
    agg1f_k<<<NN / 4, 256, 0, stream>>>(rowptr, csru, s1s, s1d,
                                        (const uint2*)h8, W2tb, a2, h2, s2s, s2d);
    agg2_k<<<(NN + 3) / 4, 256, 0, stream>>>(rowptr, csru, s2s, s2d, h2, out);
}